// Round 3
// baseline (415.614 us; speedup 1.0000x reference)
//
#include <hip/hip_runtime.h>

#define N_NODES 100000
#define N_EDGES 3200000
#define N_GRAPHS 2048
#define VOCAB 92
#define H 64
#define N_LAYERS 3

#define BUCK_BITS 7
#define BUCK_NODES (1 << BUCK_BITS)                          // 128 nodes / bucket
#define NBUCK ((N_NODES + BUCK_NODES - 1) / BUCK_NODES)      // 782

#define PART_BLOCKS 256
#define EDGES_PER_PART (N_EDGES / PART_BLOCKS)               // 12500

// layer-0 MFMA kernel geometry
#define G0_TILE 64
#define SBINS_STRIDE 100   // f32 bins stride (92 used, pad to break banks)
#define SB_STRIDE 104      // f16 tile stride (92->96 K-pad, +8 bank pad)

// fused layer kernel geometry
#define FL_TILE 32
#define A_STRIDE 72        // f16 LDS stride (64 + 8 pad -> 2-way banks, free)

typedef _Float16 half8 __attribute__((ext_vector_type(8)));
typedef float f32x4 __attribute__((ext_vector_type(4)));

// fp32 -> bf16 (round-to-nearest-even)
__device__ inline unsigned short f2bf(float f) {
    union { float f; unsigned u; } v; v.f = f;
    unsigned u = v.u;
    u += 0x7fffu + ((u >> 16) & 1u);
    return (unsigned short)(u >> 16);
}
__device__ inline float bfhi(unsigned p) {
    union { unsigned u; float f; } v; v.u = p & 0xffff0000u; return v.f;
}
__device__ inline float bflo(unsigned p) {
    union { unsigned u; float f; } v; v.u = p << 16; return v.f;
}

__device__ inline void unpack_add(uint4 v, float* a) {
    a[0] += bflo(v.x); a[1] += bfhi(v.x);
    a[2] += bflo(v.y); a[3] += bfhi(v.y);
    a[4] += bflo(v.z); a[5] += bfhi(v.z);
    a[6] += bflo(v.w); a[7] += bfhi(v.w);
}

// ---------------- kernels ----------------

// zero bucket counters + sorted_row tail pad
__global__ void k_init(int* bcnt, int* srpad) {
    int i = threadIdx.x;
    if (i < NBUCK) bcnt[i] = 0;
    if (i < 16) srpad[i] = 0;
}

// bucket histogram; also store per-block rows for binA reuse
__global__ void k_bhist(const int* __restrict__ col, int* __restrict__ bcnt,
                        int* __restrict__ blkhist) {
    __shared__ int lh[NBUCK];
    int tid = threadIdx.x;
    for (int i = tid; i < NBUCK; i += 256) lh[i] = 0;
    __syncthreads();
    int base = blockIdx.x * EDGES_PER_PART;
    for (int k = tid; k < EDGES_PER_PART; k += 256)
        atomicAdd(&lh[col[base + k] >> BUCK_BITS], 1);
    __syncthreads();
    int* myhist = blkhist + (size_t)blockIdx.x * NBUCK;
    for (int i = tid; i < NBUCK; i += 256) {
        int c = lh[i];
        myhist[i] = c;
        if (c) atomicAdd(&bcnt[i], c);
    }
}

// scan the 782 bucket counts; init reservation cursors
__global__ void k_bscan(const int* __restrict__ bcnt, int* __restrict__ bbase,
                        int* __restrict__ bcur) {
    __shared__ int s[1024];
    int tid = threadIdx.x;
    int v = (tid < NBUCK) ? bcnt[tid] : 0;
    s[tid] = v;
    __syncthreads();
    for (int off = 1; off < 1024; off <<= 1) {
        int x = (tid >= off) ? s[tid - off] : 0;
        __syncthreads();
        s[tid] += x;
        __syncthreads();
    }
    if (tid < NBUCK) {
        int e = s[tid] - v;
        bbase[tid] = e;
        bcur[tid] = e;
    }
    if (tid == 0) bbase[NBUCK] = N_EDGES;
}

// pass A: slice reservation from precomputed block hist, then rank + packed write
__global__ __launch_bounds__(1024) void k_binA(const int* __restrict__ row,
                                               const int* __restrict__ col,
                                               const int* __restrict__ blkhist,
                                               int* __restrict__ bcur,
                                               int* __restrict__ staging) {
    __shared__ int lcnt[NBUCK];
    __shared__ int lbase[NBUCK];
    int tid = threadIdx.x;
    int base = blockIdx.x * EDGES_PER_PART;
    const int* myhist = blkhist + (size_t)blockIdx.x * NBUCK;
    for (int i = tid; i < NBUCK; i += 1024) {
        int c = myhist[i];
        lbase[i] = c ? atomicAdd(&bcur[i], c) : 0;
        lcnt[i] = 0;
    }
    __syncthreads();
    for (int k = tid; k < EDGES_PER_PART; k += 1024) {
        int c = col[base + k];
        int b = c >> BUCK_BITS;
        int r = atomicAdd(&lcnt[b], 1);
        staging[lbase[b] + r] = row[base + k] | ((c & (BUCK_NODES - 1)) << 17);
    }
}

// pass B: per-bucket degree hist/scan -> degi/row_start/dinv + packed(x, dinv_bf16),
// then local sort
__global__ void k_binB(const int* __restrict__ staging, const int* __restrict__ bbase,
                       const int* __restrict__ x,
                       int* __restrict__ sorted_row, int* __restrict__ degi,
                       int* __restrict__ row_start, float* __restrict__ dinv,
                       unsigned* __restrict__ packed) {
    __shared__ int lde[BUCK_NODES];
    __shared__ int lsc[BUCK_NODES];
    int b = blockIdx.x, tid = threadIdx.x;
    int n0 = b << BUCK_BITS;
    int s0 = bbase[b], s1 = bbase[b + 1];
    if (tid < BUCK_NODES) lde[tid] = 0;
    __syncthreads();
    for (int i = s0 + tid; i < s1; i += 256)
        atomicAdd(&lde[staging[i] >> 17], 1);
    __syncthreads();
    if (tid < BUCK_NODES) lsc[tid] = lde[tid];
    __syncthreads();
    for (int off = 1; off < BUCK_NODES; off <<= 1) {
        int v = (tid >= off && tid < BUCK_NODES) ? lsc[tid - off] : 0;
        __syncthreads();
        if (tid < BUCK_NODES) lsc[tid] += v;
        __syncthreads();
    }
    if (tid < BUCK_NODES) {
        int n = n0 + tid;
        int excl = lsc[tid] - lde[tid];
        if (n < N_NODES) {
            row_start[n] = s0 + excl;
            degi[n] = lde[tid];
            float dv = rsqrtf((float)(lde[tid] + 1));
            dinv[n] = dv;
            packed[n] = ((unsigned)f2bf(dv) << 16) | (unsigned)x[n];
        }
        lsc[tid] = excl;
        lde[tid] = 0;
    }
    __syncthreads();
    for (int i = s0 + tid; i < s1; i += 256) {
        int p = staging[i];
        int ln = p >> 17;
        int r = atomicAdd(&lde[ln], 1);
        sorted_row[s0 + lsc[ln] + r] = p & 0x1FFFF;
    }
}

// M = emb @ W0 (92 x 64, f32). One block (64 threads) per vocab row.
__global__ void k_premix(const float* __restrict__ emb, const float* __restrict__ W0,
                         float* __restrict__ M) {
    int v = blockIdx.x, c = threadIdx.x;
    float acc = 0.0f;
#pragma unroll
    for (int k = 0; k < H; ++k) acc += emb[v * H + k] * W0[k * H + c];
    M[v * H + c] = acc;
}

// layer-0, vocab-factored:
//   S[n,v] = sum_{edges e->n} dinv_bf16[src] * [x[src]==v]   (incl. self-loop)
//   h[n,:] = relu(dinv[n] * (S @ M)[n,:] + b);  q[n,:] = bf16(dinv[n]*h[n,:])
__global__ __launch_bounds__(256) void k_gather0_mfma(
    const int* __restrict__ sorted_row, const int* __restrict__ row_start,
    const int* __restrict__ degi, const unsigned* __restrict__ packed,
    const float* __restrict__ M, const float* __restrict__ dinv,
    const float* __restrict__ bias, float* __restrict__ h,
    unsigned short* __restrict__ qout) {
    __shared__ float Sbins[G0_TILE][SBINS_STRIDE];   // f32 accumulation bins
    __shared__ _Float16 Sb[G0_TILE][SB_STRIDE];      // A operand (nodes x K)
    __shared__ _Float16 Blds[H][SB_STRIDE];          // B operand, stored as M^T (cols x K)
    __shared__ int sstart[G0_TILE];
    __shared__ int sdeg[G0_TILE];

    int tid = threadIdx.x;
    int n0 = blockIdx.x * G0_TILE;

    for (int i = tid; i < G0_TILE * SBINS_STRIDE; i += 256)
        ((float*)Sbins)[i] = 0.0f;
    {
        int c = tid & 63, v0 = tid >> 6;
        for (int v = v0; v < VOCAB; v += 4)
            Blds[c][v] = (_Float16)M[v * H + c];
        Blds[c][VOCAB + v0] = (_Float16)0.0f;
    }
    if (tid < G0_TILE) {
        int n = n0 + tid;
        sdeg[tid] = (n < N_NODES) ? degi[n] : 0;
        sstart[tid] = (n < N_NODES) ? row_start[n] : 0;
    }
    __syncthreads();

    int w = tid >> 6, lane = tid & 63;

    if (tid < G0_TILE) {
        int n = n0 + tid;
        if (n < N_NODES) {
            unsigned p = packed[n];
            atomicAdd(&Sbins[tid][p & 127u], __uint_as_float(p & 0xffff0000u));
        }
    }
    for (int ni = 0; ni < 16; ++ni) {
        int nl = (w << 4) + ni;
        int d = sdeg[nl];
        int st = sstart[nl];
        for (int e = lane; e < d; e += 64) {
            unsigned p = packed[sorted_row[st + e]];
            atomicAdd(&Sbins[nl][p & 127u], __uint_as_float(p & 0xffff0000u));
        }
    }
    __syncthreads();

    {
        int r0 = tid >> 2, k0 = (tid & 3) * 24;
#pragma unroll
        for (int m = 0; m < 3; ++m) {
            f32x4 f0 = *(const f32x4*)&Sbins[r0][k0 + 8 * m];
            f32x4 f1 = *(const f32x4*)&Sbins[r0][k0 + 8 * m + 4];
            half8 o;
            o[0] = (_Float16)f0[0]; o[1] = (_Float16)f0[1];
            o[2] = (_Float16)f0[2]; o[3] = (_Float16)f0[3];
            o[4] = (_Float16)f1[0]; o[5] = (_Float16)f1[1];
            o[6] = (_Float16)f1[2]; o[7] = (_Float16)f1[3];
            *(half8*)&Sb[r0][k0 + 8 * m] = o;
        }
    }
    __syncthreads();

    int l15 = lane & 15, l4 = lane >> 4;
    half8 afr[3];
#pragma unroll
    for (int ks = 0; ks < 3; ++ks)
        afr[ks] = *(const half8*)&Sb[(w << 4) + l15][ks * 32 + l4 * 8];

    f32x4 acc[4];
#pragma unroll
    for (int c = 0; c < 4; ++c) {
        f32x4 a = {0.0f, 0.0f, 0.0f, 0.0f};
#pragma unroll
        for (int ks = 0; ks < 3; ++ks) {
            half8 bfr = *(const half8*)&Blds[c * 16 + l15][ks * 32 + l4 * 8];
            a = __builtin_amdgcn_mfma_f32_16x16x32_f16(afr[ks], bfr, a, 0, 0, 0);
        }
        acc[c] = a;
    }

    int rbase = (w << 4) + l4 * 4;
    float di4[4];
#pragma unroll
    for (int r = 0; r < 4; ++r) {
        int n = n0 + rbase + r;
        di4[r] = (n < N_NODES) ? dinv[n] : 0.0f;
    }
#pragma unroll
    for (int c = 0; c < 4; ++c) {
        float bb = bias[c * 16 + l15];
#pragma unroll
        for (int r = 0; r < 4; ++r) {
            int n = n0 + rbase + r;
            if (n < N_NODES) {
                float v = fmaxf(acc[c][r] * di4[r] + bb, 0.0f);
                h[(size_t)n * H + c * 16 + l15] = v;
                qout[(size_t)n * H + c * 16 + l15] = f2bf(di4[r] * v);
            }
        }
    }
}

// fused GCN layer (layers 1,2):
//   A[n,:] = sum_{e->n} q[src] + q[n]       (q = bf16(dinv*h), 16B-granule gather)
//   z = A @ W  (MFMA, f16)
//   h[n,:] += relu(dinv[n]*z + b);   qout[n,:] = bf16(dinv[n]*h[n,:])  (if !last)
// FL_TILE=32 / 8 nodes per wave: grid 3125, LDS ~14 KB -> 8 blocks/CU (full occ).
// sorted_row index loads for chunk k+1 are prefetched while chunk k's gathers
// are in flight (sorted_row has a 16-int zero pad; tail lanes masked).
__global__ __launch_bounds__(256, 8) void k_fused(
    const int* __restrict__ sorted_row, const int* __restrict__ row_start,
    const int* __restrict__ degi, const unsigned* __restrict__ q,
    const float* __restrict__ dinv, const float* __restrict__ W,
    const float* __restrict__ bias, float* __restrict__ h,
    unsigned short* __restrict__ qout, int last) {
    __shared__ _Float16 Alds[FL_TILE][A_STRIDE];
    __shared__ _Float16 Blds[H][A_STRIDE];

    int tid = threadIdx.x;
    int n0 = blockIdx.x * FL_TILE;

    // stage B = W^T in f16 (B frag: lane l -> B[k][l&15], k-contiguous 8)
    {
        int c = tid & 63, k0 = (tid >> 6) * 16;
#pragma unroll
        for (int k = 0; k < 16; ++k)
            Blds[c][k0 + k] = (_Float16)W[(k0 + k) * H + c];
    }

    int w = tid >> 6, lane = tid & 63;
    int s = lane >> 3;   // edge slot 0..7
    int j = lane & 7;    // 16B granule within row (channels 8j..8j+7)
    const uint4* q4 = (const uint4*)q;

    // gather phase: wave w owns nodes w*8..w*8+7; 16 edges in flight + index prefetch
    for (int ni = 0; ni < 8; ++ni) {
        int nl = (w << 3) + ni;
        int n = n0 + nl;
        int d = 0, st = 0;
        if (n < N_NODES) { d = degi[n]; st = row_start[n]; }
        const int* srp = sorted_row + st;
        float a[8];
#pragma unroll
        for (int k = 0; k < 8; ++k) a[k] = 0.0f;

        // prime the index pipeline (safe: 16-int zero pad past N_EDGES)
        int srA = __builtin_nontemporal_load(&srp[s]);
        int srB = __builtin_nontemporal_load(&srp[8 + s]);
        int e = 0;
        for (; e + 16 <= d; e += 16) {
            uint4 va = q4[(size_t)srA * 8 + j];
            uint4 vb = q4[(size_t)srB * 8 + j];
            srA = __builtin_nontemporal_load(&srp[e + 16 + s]);
            srB = __builtin_nontemporal_load(&srp[e + 24 + s]);
            unpack_add(va, a);
            unpack_add(vb, a);
        }
        if (e < d) {  // masked tail (indices already prefetched)
            uint4 va = q4[(size_t)srA * 8 + j];
            uint4 vb = q4[(size_t)srB * 8 + j];
            if (e + s >= d) { va.x = 0; va.y = 0; va.z = 0; va.w = 0; }
            if (e + 8 + s >= d) { vb.x = 0; vb.y = 0; vb.z = 0; vb.w = 0; }
            unpack_add(va, a);
            unpack_add(vb, a);
        }
        // reduce across the 8 slots
#pragma unroll
        for (int k = 0; k < 8; ++k) a[k] += __shfl_xor(a[k], 8, 64);
#pragma unroll
        for (int k = 0; k < 8; ++k) a[k] += __shfl_xor(a[k], 16, 64);
#pragma unroll
        for (int k = 0; k < 8; ++k) a[k] += __shfl_xor(a[k], 32, 64);
        if (s == 0) {
            if (n < N_NODES) {  // self-loop term
                uint4 vs = q4[(size_t)n * 8 + j];
                unpack_add(vs, a);
            }
            half8 o;
#pragma unroll
            for (int k = 0; k < 8; ++k) o[k] = (_Float16)a[k];
            *(half8*)&Alds[nl][j * 8] = o;
        }
    }
    __syncthreads();

    // MFMA: waves 0,1 -> output rows [w*16, w*16+16) x 64 cols; K=64
    if (w < 2) {
        int l15 = lane & 15, l4 = lane >> 4;
        half8 afr[2];
#pragma unroll
        for (int ks = 0; ks < 2; ++ks)
            afr[ks] = *(const half8*)&Alds[(w << 4) + l15][ks * 32 + l4 * 8];

        f32x4 acc[4];
#pragma unroll
        for (int c = 0; c < 4; ++c) {
            f32x4 a = {0.0f, 0.0f, 0.0f, 0.0f};
#pragma unroll
            for (int ks = 0; ks < 2; ++ks) {
                half8 bfr = *(const half8*)&Blds[c * 16 + l15][ks * 32 + l4 * 8];
                a = __builtin_amdgcn_mfma_f32_16x16x32_f16(afr[ks], bfr, a, 0, 0, 0);
            }
            acc[c] = a;
        }

        // epilogue: h += relu(acc*dinv + b); qout = bf16(dinv*h)  (nontemporal:
        // keep L2 for the q gather table)
        int rbase = (w << 4) + l4 * 4;
        float di4[4];
#pragma unroll
        for (int r = 0; r < 4; ++r) {
            int n = n0 + rbase + r;
            di4[r] = (n < N_NODES) ? dinv[n] : 0.0f;
        }
#pragma unroll
        for (int c = 0; c < 4; ++c) {
            float bb = bias[c * 16 + l15];
#pragma unroll
            for (int r = 0; r < 4; ++r) {
                int n = n0 + rbase + r;
                if (n < N_NODES) {
                    size_t idx = (size_t)n * H + c * 16 + l15;
                    float v = __builtin_nontemporal_load(&h[idx]) +
                              fmaxf(acc[c][r] * di4[r] + bb, 0.0f);
                    __builtin_nontemporal_store(v, &h[idx]);
                    if (!last)
                        __builtin_nontemporal_store(f2bf(di4[r] * v), &qout[idx]);
                }
            }
        }
    }
}

// fused mean-pool + MLP: one wave per graph (batch sorted -> binary search)
__global__ void k_poolmlp(const float* __restrict__ h, const int* __restrict__ batch,
                          const float* __restrict__ w1, const float* __restrict__ b1,
                          const float* __restrict__ w2, const float* __restrict__ b2,
                          const float* __restrict__ w3, const float* __restrict__ b3,
                          float* __restrict__ out) {
    __shared__ float sg[H];
    __shared__ float s1[32];
    __shared__ float s2[16];
    int g = blockIdx.x, tid = threadIdx.x;
    int lo = 0, hi = N_NODES;
    while (lo < hi) { int mid = (lo + hi) >> 1; if (batch[mid] < g) lo = mid + 1; else hi = mid; }
    int lo2 = lo, hi2 = N_NODES;
    while (lo2 < hi2) { int mid = (lo2 + hi2) >> 1; if (batch[mid] < g + 1) lo2 = mid + 1; else hi2 = mid; }
    float acc = 0.0f;
    for (int n = lo; n < lo2; ++n) acc += h[(size_t)n * H + tid];
    float cntf = (float)(lo2 - lo);
    sg[tid] = acc / fmaxf(cntf, 1.0f);
    __syncthreads();
    if (tid < 32) {
        float a = b1[tid];
#pragma unroll
        for (int k = 0; k < H; ++k) a += sg[k] * w1[k * 32 + tid];
        s1[tid] = fmaxf(a, 0.0f);
    }
    __syncthreads();
    if (tid < 16) {
        float a = b2[tid];
#pragma unroll
        for (int k = 0; k < 32; ++k) a += s1[k] * w2[k * 16 + tid];
        s2[tid] = fmaxf(a, 0.0f);
    }
    __syncthreads();
    if (tid == 0) {
        float a = b3[0];
#pragma unroll
        for (int k = 0; k < 16; ++k) a += s2[k] * w3[k];
        out[g] = a;
    }
}

// ---------------- launch ----------------

extern "C" void kernel_launch(void* const* d_in, const int* in_sizes, int n_in,
                              void* d_out, int out_size, void* d_ws, size_t ws_size,
                              hipStream_t stream) {
    const int*   x      = (const int*)d_in[0];
    const int*   eidx   = (const int*)d_in[1];   // (2, E): row = eidx, col = eidx + E
    const int*   batch  = (const int*)d_in[2];
    const float* emb    = (const float*)d_in[3];
    const float* conv_w = (const float*)d_in[4];
    const float* conv_b = (const float*)d_in[5];
    const float* w1     = (const float*)d_in[6];
    const float* b1     = (const float*)d_in[7];
    const float* w2     = (const float*)d_in[8];
    const float* b2     = (const float*)d_in[9];
    const float* w3     = (const float*)d_in[10];
    const float* b3     = (const float*)d_in[11];
    float* out = (float*)d_out;

    const int* row = eidx;
    const int* col = eidx + N_EDGES;

    // workspace layout (4-byte units)
    char* wsb = (char*)d_ws;
    size_t off = 0;
    auto alloc = [&](size_t elems) { void* p = wsb + off; off += ((elems * 4 + 255) & ~(size_t)255); return p; };
    int*      bcnt       = (int*)alloc(NBUCK);
    int*      bbase      = (int*)alloc(NBUCK + 1);
    int*      bcur       = (int*)alloc(NBUCK);
    int*      blkhist    = (int*)alloc((size_t)PART_BLOCKS * NBUCK);
    int*      row_start  = (int*)alloc(N_NODES);
    int*      degi       = (int*)alloc(N_NODES);
    float*    dinv       = (float*)alloc(N_NODES);
    unsigned* packed     = (unsigned*)alloc(N_NODES);
    float*    M          = (float*)alloc(VOCAB * H);
    int*      sorted_row = (int*)alloc(N_EDGES + 16);            // +16 zero pad
    float*    h          = (float*)alloc((size_t)N_NODES * H);
    unsigned short* qa   = (unsigned short*)alloc((size_t)N_NODES * H / 2);  // bf16
    unsigned short* qb   = (unsigned short*)alloc((size_t)N_NODES * H / 2);  // bf16

    // packed staging (int[N_EDGES] = 12.8 MB) aliases qa (dead until k_gather0 writes)
    int* staging = (int*)qa;

    const int B = 256;
    const int gT = (N_NODES + G0_TILE - 1) / G0_TILE;   // 1563
    const int gF = (N_NODES + FL_TILE - 1) / FL_TILE;   // 3125

    hipLaunchKernelGGL(k_init, dim3(1), dim3(1024), 0, stream, bcnt, sorted_row + N_EDGES);
    hipLaunchKernelGGL(k_bhist, dim3(PART_BLOCKS), dim3(256), 0, stream, col, bcnt, blkhist);
    hipLaunchKernelGGL(k_bscan, dim3(1), dim3(1024), 0, stream, bcnt, bbase, bcur);
    hipLaunchKernelGGL(k_binA, dim3(PART_BLOCKS), dim3(1024), 0, stream,
                       row, col, blkhist, bcur, staging);
    hipLaunchKernelGGL(k_binB, dim3(NBUCK), dim3(256), 0, stream, staging, bbase, x,
                       sorted_row, degi, row_start, dinv, packed);

    // layer 0: vocabulary-factored, S-bins + MFMA; also emits q = bf16(dinv*h)
    hipLaunchKernelGGL(k_premix, dim3(VOCAB), dim3(H), 0, stream, emb, conv_w, M);
    hipLaunchKernelGGL(k_gather0_mfma, dim3(gT), dim3(B), 0, stream,
                       sorted_row, row_start, degi, packed, M, dinv, conv_b, h, qa);

    // layers 1,2: fused gather + MFMA transform (h@W commutes with aggregation)
    hipLaunchKernelGGL(k_fused, dim3(gF), dim3(B), 0, stream,
                       sorted_row, row_start, degi, (const unsigned*)qa, dinv,
                       conv_w + (size_t)1 * H * H, conv_b + 1 * H, h, qb, 0);
    hipLaunchKernelGGL(k_fused, dim3(gF), dim3(B), 0, stream,
                       sorted_row, row_start, degi, (const unsigned*)qb, dinv,
                       conv_w + (size_t)2 * H * H, conv_b + 2 * H, h, qa, 1);

    hipLaunchKernelGGL(k_poolmlp, dim3(N_GRAPHS), dim3(64), 0, stream,
                       h, batch, w1, b1, w2, b2, w3, b3, out);

    (void)in_sizes; (void)n_in; (void)out_size; (void)ws_size;
}

// Round 4
// 380.765 us; speedup vs baseline: 1.0915x; 1.0915x over previous
//
#include <hip/hip_runtime.h>

#define N_NODES 100000
#define N_EDGES 3200000
#define N_GRAPHS 2048
#define VOCAB 92
#define H 64
#define N_LAYERS 3

#define BUCK_BITS 7
#define BUCK_NODES (1 << BUCK_BITS)                          // 128 nodes / bucket
#define NBUCK ((N_NODES + BUCK_NODES - 1) / BUCK_NODES)      // 782

#define PART_BLOCKS 256
#define EDGES_PER_PART (N_EDGES / PART_BLOCKS)               // 12500

// layer-0 MFMA kernel geometry
#define G0_TILE 64
#define SBINS_STRIDE 100   // f32 bins stride (92 used, pad to break banks)
#define SB_STRIDE 104      // f16 tile stride (92->96 K-pad, +8 bank pad)

// fused layer kernel geometry
#define FL_TILE 64
#define A_STRIDE 72        // f16 LDS stride (64 + 8 pad -> 2-way banks, free)

typedef _Float16 half8 __attribute__((ext_vector_type(8)));
typedef float f32x4 __attribute__((ext_vector_type(4)));

// fp32 -> bf16 (round-to-nearest-even)
__device__ inline unsigned short f2bf(float f) {
    union { float f; unsigned u; } v; v.f = f;
    unsigned u = v.u;
    u += 0x7fffu + ((u >> 16) & 1u);
    return (unsigned short)(u >> 16);
}
__device__ inline float bfhi(unsigned p) {
    union { unsigned u; float f; } v; v.u = p & 0xffff0000u; return v.f;
}
__device__ inline float bflo(unsigned p) {
    union { unsigned u; float f; } v; v.u = p << 16; return v.f;
}

__device__ inline void unpack_add(uint4 v, float* a) {
    a[0] += bflo(v.x); a[1] += bfhi(v.x);
    a[2] += bflo(v.y); a[3] += bfhi(v.y);
    a[4] += bflo(v.z); a[5] += bfhi(v.z);
    a[6] += bflo(v.w); a[7] += bfhi(v.w);
}

// ---------------- kernels ----------------

// zero bucket counters + sorted_row tail pad
__global__ void k_init(int* bcnt, int* srpad) {
    int i = threadIdx.x;
    if (i < NBUCK) bcnt[i] = 0;
    if (i < 16) srpad[i] = 0;
}

// bucket histogram; also store per-block rows for binA reuse
__global__ void k_bhist(const int* __restrict__ col, int* __restrict__ bcnt,
                        int* __restrict__ blkhist) {
    __shared__ int lh[NBUCK];
    int tid = threadIdx.x;
    for (int i = tid; i < NBUCK; i += 256) lh[i] = 0;
    __syncthreads();
    int base = blockIdx.x * EDGES_PER_PART;
    for (int k = tid; k < EDGES_PER_PART; k += 256)
        atomicAdd(&lh[col[base + k] >> BUCK_BITS], 1);
    __syncthreads();
    int* myhist = blkhist + (size_t)blockIdx.x * NBUCK;
    for (int i = tid; i < NBUCK; i += 256) {
        int c = lh[i];
        myhist[i] = c;
        if (c) atomicAdd(&bcnt[i], c);
    }
}

// scan the 782 bucket counts; init reservation cursors
__global__ void k_bscan(const int* __restrict__ bcnt, int* __restrict__ bbase,
                        int* __restrict__ bcur) {
    __shared__ int s[1024];
    int tid = threadIdx.x;
    int v = (tid < NBUCK) ? bcnt[tid] : 0;
    s[tid] = v;
    __syncthreads();
    for (int off = 1; off < 1024; off <<= 1) {
        int x = (tid >= off) ? s[tid - off] : 0;
        __syncthreads();
        s[tid] += x;
        __syncthreads();
    }
    if (tid < NBUCK) {
        int e = s[tid] - v;
        bbase[tid] = e;
        bcur[tid] = e;
    }
    if (tid == 0) bbase[NBUCK] = N_EDGES;
}

// pass A: slice reservation from precomputed block hist, then rank + packed write
__global__ __launch_bounds__(1024) void k_binA(const int* __restrict__ row,
                                               const int* __restrict__ col,
                                               const int* __restrict__ blkhist,
                                               int* __restrict__ bcur,
                                               int* __restrict__ staging) {
    __shared__ int lcnt[NBUCK];
    __shared__ int lbase[NBUCK];
    int tid = threadIdx.x;
    int base = blockIdx.x * EDGES_PER_PART;
    const int* myhist = blkhist + (size_t)blockIdx.x * NBUCK;
    for (int i = tid; i < NBUCK; i += 1024) {
        int c = myhist[i];
        lbase[i] = c ? atomicAdd(&bcur[i], c) : 0;
        lcnt[i] = 0;
    }
    __syncthreads();
    for (int k = tid; k < EDGES_PER_PART; k += 1024) {
        int c = col[base + k];
        int b = c >> BUCK_BITS;
        int r = atomicAdd(&lcnt[b], 1);
        staging[lbase[b] + r] = row[base + k] | ((c & (BUCK_NODES - 1)) << 17);
    }
}

// pass B: per-bucket degree hist/scan -> degi/row_start/dinv + packed(x, dinv_bf16),
// then local sort
__global__ void k_binB(const int* __restrict__ staging, const int* __restrict__ bbase,
                       const int* __restrict__ x,
                       int* __restrict__ sorted_row, int* __restrict__ degi,
                       int* __restrict__ row_start, float* __restrict__ dinv,
                       unsigned* __restrict__ packed) {
    __shared__ int lde[BUCK_NODES];
    __shared__ int lsc[BUCK_NODES];
    int b = blockIdx.x, tid = threadIdx.x;
    int n0 = b << BUCK_BITS;
    int s0 = bbase[b], s1 = bbase[b + 1];
    if (tid < BUCK_NODES) lde[tid] = 0;
    __syncthreads();
    for (int i = s0 + tid; i < s1; i += 256)
        atomicAdd(&lde[staging[i] >> 17], 1);
    __syncthreads();
    if (tid < BUCK_NODES) lsc[tid] = lde[tid];
    __syncthreads();
    for (int off = 1; off < BUCK_NODES; off <<= 1) {
        int v = (tid >= off && tid < BUCK_NODES) ? lsc[tid - off] : 0;
        __syncthreads();
        if (tid < BUCK_NODES) lsc[tid] += v;
        __syncthreads();
    }
    if (tid < BUCK_NODES) {
        int n = n0 + tid;
        int excl = lsc[tid] - lde[tid];
        if (n < N_NODES) {
            row_start[n] = s0 + excl;
            degi[n] = lde[tid];
            float dv = rsqrtf((float)(lde[tid] + 1));
            dinv[n] = dv;
            packed[n] = ((unsigned)f2bf(dv) << 16) | (unsigned)x[n];
        }
        lsc[tid] = excl;
        lde[tid] = 0;
    }
    __syncthreads();
    for (int i = s0 + tid; i < s1; i += 256) {
        int p = staging[i];
        int ln = p >> 17;
        int r = atomicAdd(&lde[ln], 1);
        sorted_row[s0 + lsc[ln] + r] = p & 0x1FFFF;
    }
}

// M = emb @ W0 (92 x 64, f32). One block (64 threads) per vocab row.
__global__ void k_premix(const float* __restrict__ emb, const float* __restrict__ W0,
                         float* __restrict__ M) {
    int v = blockIdx.x, c = threadIdx.x;
    float acc = 0.0f;
#pragma unroll
    for (int k = 0; k < H; ++k) acc += emb[v * H + k] * W0[k * H + c];
    M[v * H + c] = acc;
}

// layer-0, vocab-factored:
//   S[n,v] = sum_{edges e->n} dinv_bf16[src] * [x[src]==v]   (incl. self-loop)
//   h[n,:] = relu(dinv[n] * (S @ M)[n,:] + b);  q[n,:] = bf16(dinv[n]*h[n,:])
__global__ __launch_bounds__(256) void k_gather0_mfma(
    const int* __restrict__ sorted_row, const int* __restrict__ row_start,
    const int* __restrict__ degi, const unsigned* __restrict__ packed,
    const float* __restrict__ M, const float* __restrict__ dinv,
    const float* __restrict__ bias, float* __restrict__ h,
    unsigned short* __restrict__ qout) {
    __shared__ float Sbins[G0_TILE][SBINS_STRIDE];   // f32 accumulation bins
    __shared__ _Float16 Sb[G0_TILE][SB_STRIDE];      // A operand (nodes x K)
    __shared__ _Float16 Blds[H][SB_STRIDE];          // B operand, stored as M^T (cols x K)
    __shared__ int sstart[G0_TILE];
    __shared__ int sdeg[G0_TILE];

    int tid = threadIdx.x;
    int n0 = blockIdx.x * G0_TILE;

    for (int i = tid; i < G0_TILE * SBINS_STRIDE; i += 256)
        ((float*)Sbins)[i] = 0.0f;
    {
        int c = tid & 63, v0 = tid >> 6;
        for (int v = v0; v < VOCAB; v += 4)
            Blds[c][v] = (_Float16)M[v * H + c];
        Blds[c][VOCAB + v0] = (_Float16)0.0f;
    }
    if (tid < G0_TILE) {
        int n = n0 + tid;
        sdeg[tid] = (n < N_NODES) ? degi[n] : 0;
        sstart[tid] = (n < N_NODES) ? row_start[n] : 0;
    }
    __syncthreads();

    int w = tid >> 6, lane = tid & 63;

    if (tid < G0_TILE) {
        int n = n0 + tid;
        if (n < N_NODES) {
            unsigned p = packed[n];
            atomicAdd(&Sbins[tid][p & 127u], __uint_as_float(p & 0xffff0000u));
        }
    }
    for (int ni = 0; ni < 16; ++ni) {
        int nl = (w << 4) + ni;
        int d = sdeg[nl];
        int st = sstart[nl];
        for (int e = lane; e < d; e += 64) {
            unsigned p = packed[sorted_row[st + e]];
            atomicAdd(&Sbins[nl][p & 127u], __uint_as_float(p & 0xffff0000u));
        }
    }
    __syncthreads();

    {
        int r0 = tid >> 2, k0 = (tid & 3) * 24;
#pragma unroll
        for (int m = 0; m < 3; ++m) {
            f32x4 f0 = *(const f32x4*)&Sbins[r0][k0 + 8 * m];
            f32x4 f1 = *(const f32x4*)&Sbins[r0][k0 + 8 * m + 4];
            half8 o;
            o[0] = (_Float16)f0[0]; o[1] = (_Float16)f0[1];
            o[2] = (_Float16)f0[2]; o[3] = (_Float16)f0[3];
            o[4] = (_Float16)f1[0]; o[5] = (_Float16)f1[1];
            o[6] = (_Float16)f1[2]; o[7] = (_Float16)f1[3];
            *(half8*)&Sb[r0][k0 + 8 * m] = o;
        }
    }
    __syncthreads();

    int l15 = lane & 15, l4 = lane >> 4;
    half8 afr[3];
#pragma unroll
    for (int ks = 0; ks < 3; ++ks)
        afr[ks] = *(const half8*)&Sb[(w << 4) + l15][ks * 32 + l4 * 8];

    f32x4 acc[4];
#pragma unroll
    for (int c = 0; c < 4; ++c) {
        f32x4 a = {0.0f, 0.0f, 0.0f, 0.0f};
#pragma unroll
        for (int ks = 0; ks < 3; ++ks) {
            half8 bfr = *(const half8*)&Blds[c * 16 + l15][ks * 32 + l4 * 8];
            a = __builtin_amdgcn_mfma_f32_16x16x32_f16(afr[ks], bfr, a, 0, 0, 0);
        }
        acc[c] = a;
    }

    int rbase = (w << 4) + l4 * 4;
    float di4[4];
#pragma unroll
    for (int r = 0; r < 4; ++r) {
        int n = n0 + rbase + r;
        di4[r] = (n < N_NODES) ? dinv[n] : 0.0f;
    }
#pragma unroll
    for (int c = 0; c < 4; ++c) {
        float bb = bias[c * 16 + l15];
#pragma unroll
        for (int r = 0; r < 4; ++r) {
            int n = n0 + rbase + r;
            if (n < N_NODES) {
                float v = fmaxf(acc[c][r] * di4[r] + bb, 0.0f);
                h[(size_t)n * H + c * 16 + l15] = v;
                qout[(size_t)n * H + c * 16 + l15] = f2bf(di4[r] * v);
            }
        }
    }
}

// fused GCN layer (layers 1,2):
//   A[n,:] = sum_{e->n} q[src] + q[n]       (q = bf16(dinv*h), 16B-granule gather)
//   z = A @ W  (MFMA, f16)
//   h[n,:] += relu(dinv[n]*z + b);   qout[n,:] = bf16(dinv[n]*h[n,:])  (if !last)
// 8 waves/block (512 thr), FL_TILE=64: 8 nodes per wave in the gather phase,
// MFMA split 8 ways (16 rows x 32 cols each). sorted_row indices for chunk k+1
// prefetched while chunk k's gathers are in flight (16-int zero pad; tail masked).
// NO nontemporal hints: NT stores on h/qout evicted L2 and cost +25MB FETCH (R3).
__global__ __launch_bounds__(512) void k_fused(
    const int* __restrict__ sorted_row, const int* __restrict__ row_start,
    const int* __restrict__ degi, const unsigned* __restrict__ q,
    const float* __restrict__ dinv, const float* __restrict__ W,
    const float* __restrict__ bias, float* __restrict__ h,
    unsigned short* __restrict__ qout, int last) {
    __shared__ _Float16 Alds[FL_TILE][A_STRIDE];
    __shared__ _Float16 Blds[H][A_STRIDE];

    int tid = threadIdx.x;
    int n0 = blockIdx.x * FL_TILE;

    // stage B = W^T in f16 (B frag: lane l -> B[k][l&15], k-contiguous 8)
    {
        int c = tid & 63, k0 = (tid >> 6) * 8;
#pragma unroll
        for (int k = 0; k < 8; ++k)
            Blds[c][k0 + k] = (_Float16)W[(k0 + k) * H + c];
    }

    int w = tid >> 6, lane = tid & 63;
    int s = lane >> 3;   // edge slot 0..7
    int j = lane & 7;    // 16B granule within row (channels 8j..8j+7)
    const uint4* q4 = (const uint4*)q;

    // gather phase: wave w owns nodes w*8..w*8+7; 16 edges in flight + index prefetch
    for (int ni = 0; ni < 8; ++ni) {
        int nl = (w << 3) + ni;
        int n = n0 + nl;
        int d = 0, st = 0;
        if (n < N_NODES) { d = degi[n]; st = row_start[n]; }
        const int* srp = sorted_row + st;
        float a[8];
#pragma unroll
        for (int k = 0; k < 8; ++k) a[k] = 0.0f;

        // prime the index pipeline (safe: 16-int zero pad past N_EDGES)
        int srA = srp[s];
        int srB = srp[8 + s];
        int e = 0;
        for (; e + 16 <= d; e += 16) {
            uint4 va = q4[(size_t)srA * 8 + j];
            uint4 vb = q4[(size_t)srB * 8 + j];
            srA = srp[e + 16 + s];
            srB = srp[e + 24 + s];
            unpack_add(va, a);
            unpack_add(vb, a);
        }
        if (e < d) {  // masked tail (indices already prefetched)
            uint4 va = q4[(size_t)srA * 8 + j];
            uint4 vb = q4[(size_t)srB * 8 + j];
            if (e + s >= d) { va.x = 0; va.y = 0; va.z = 0; va.w = 0; }
            if (e + 8 + s >= d) { vb.x = 0; vb.y = 0; vb.z = 0; vb.w = 0; }
            unpack_add(va, a);
            unpack_add(vb, a);
        }
        // reduce across the 8 slots
#pragma unroll
        for (int k = 0; k < 8; ++k) a[k] += __shfl_xor(a[k], 8, 64);
#pragma unroll
        for (int k = 0; k < 8; ++k) a[k] += __shfl_xor(a[k], 16, 64);
#pragma unroll
        for (int k = 0; k < 8; ++k) a[k] += __shfl_xor(a[k], 32, 64);
        if (s == 0) {
            if (n < N_NODES) {  // self-loop term
                uint4 vs = q4[(size_t)n * 8 + j];
                unpack_add(vs, a);
            }
            half8 o;
#pragma unroll
            for (int k = 0; k < 8; ++k) o[k] = (_Float16)a[k];
            *(half8*)&Alds[nl][j * 8] = o;
        }
    }
    __syncthreads();

    // MFMA: wave w -> output rows [(w&3)*16, +16) x cols [(w>>2)*32, +32); K=64
    int l15 = lane & 15, l4 = lane >> 4;
    int rw = (w & 3) << 4;       // row base
    int cb = (w >> 2) << 1;      // col block base (of 16-wide col groups)
    half8 afr[2];
#pragma unroll
    for (int ks = 0; ks < 2; ++ks)
        afr[ks] = *(const half8*)&Alds[rw + l15][ks * 32 + l4 * 8];

    f32x4 acc[2];
#pragma unroll
    for (int ci = 0; ci < 2; ++ci) {
        f32x4 a = {0.0f, 0.0f, 0.0f, 0.0f};
#pragma unroll
        for (int ks = 0; ks < 2; ++ks) {
            half8 bfr = *(const half8*)&Blds[(cb + ci) * 16 + l15][ks * 32 + l4 * 8];
            a = __builtin_amdgcn_mfma_f32_16x16x32_f16(afr[ks], bfr, a, 0, 0, 0);
        }
        acc[ci] = a;
    }

    // epilogue: h += relu(acc*dinv + b); qout = bf16(dinv*h)
    int rbase = rw + l4 * 4;
    float di4[4];
#pragma unroll
    for (int r = 0; r < 4; ++r) {
        int n = n0 + rbase + r;
        di4[r] = (n < N_NODES) ? dinv[n] : 0.0f;
    }
#pragma unroll
    for (int ci = 0; ci < 2; ++ci) {
        float bb = bias[(cb + ci) * 16 + l15];
#pragma unroll
        for (int r = 0; r < 4; ++r) {
            int n = n0 + rbase + r;
            if (n < N_NODES) {
                size_t idx = (size_t)n * H + (cb + ci) * 16 + l15;
                float v = h[idx] + fmaxf(acc[ci][r] * di4[r] + bb, 0.0f);
                h[idx] = v;
                if (!last) qout[idx] = f2bf(di4[r] * v);
            }
        }
    }
}

// fused mean-pool + MLP: one wave per graph (batch sorted -> binary search)
__global__ void k_poolmlp(const float* __restrict__ h, const int* __restrict__ batch,
                          const float* __restrict__ w1, const float* __restrict__ b1,
                          const float* __restrict__ w2, const float* __restrict__ b2,
                          const float* __restrict__ w3, const float* __restrict__ b3,
                          float* __restrict__ out) {
    __shared__ float sg[H];
    __shared__ float s1[32];
    __shared__ float s2[16];
    int g = blockIdx.x, tid = threadIdx.x;
    int lo = 0, hi = N_NODES;
    while (lo < hi) { int mid = (lo + hi) >> 1; if (batch[mid] < g) lo = mid + 1; else hi = mid; }
    int lo2 = lo, hi2 = N_NODES;
    while (lo2 < hi2) { int mid = (lo2 + hi2) >> 1; if (batch[mid] < g + 1) lo2 = mid + 1; else hi2 = mid; }
    float acc = 0.0f;
    for (int n = lo; n < lo2; ++n) acc += h[(size_t)n * H + tid];
    float cntf = (float)(lo2 - lo);
    sg[tid] = acc / fmaxf(cntf, 1.0f);
    __syncthreads();
    if (tid < 32) {
        float a = b1[tid];
#pragma unroll
        for (int k = 0; k < H; ++k) a += sg[k] * w1[k * 32 + tid];
        s1[tid] = fmaxf(a, 0.0f);
    }
    __syncthreads();
    if (tid < 16) {
        float a = b2[tid];
#pragma unroll
        for (int k = 0; k < 32; ++k) a += s1[k] * w2[k * 16 + tid];
        s2[tid] = fmaxf(a, 0.0f);
    }
    __syncthreads();
    if (tid == 0) {
        float a = b3[0];
#pragma unroll
        for (int k = 0; k < 16; ++k) a += s2[k] * w3[k];
        out[g] = a;
    }
}

// ---------------- launch ----------------

extern "C" void kernel_launch(void* const* d_in, const int* in_sizes, int n_in,
                              void* d_out, int out_size, void* d_ws, size_t ws_size,
                              hipStream_t stream) {
    const int*   x      = (const int*)d_in[0];
    const int*   eidx   = (const int*)d_in[1];   // (2, E): row = eidx, col = eidx + E
    const int*   batch  = (const int*)d_in[2];
    const float* emb    = (const float*)d_in[3];
    const float* conv_w = (const float*)d_in[4];
    const float* conv_b = (const float*)d_in[5];
    const float* w1     = (const float*)d_in[6];
    const float* b1     = (const float*)d_in[7];
    const float* w2     = (const float*)d_in[8];
    const float* b2     = (const float*)d_in[9];
    const float* w3     = (const float*)d_in[10];
    const float* b3     = (const float*)d_in[11];
    float* out = (float*)d_out;

    const int* row = eidx;
    const int* col = eidx + N_EDGES;

    // workspace layout (4-byte units)
    char* wsb = (char*)d_ws;
    size_t off = 0;
    auto alloc = [&](size_t elems) { void* p = wsb + off; off += ((elems * 4 + 255) & ~(size_t)255); return p; };
    int*      bcnt       = (int*)alloc(NBUCK);
    int*      bbase      = (int*)alloc(NBUCK + 1);
    int*      bcur       = (int*)alloc(NBUCK);
    int*      blkhist    = (int*)alloc((size_t)PART_BLOCKS * NBUCK);
    int*      row_start  = (int*)alloc(N_NODES);
    int*      degi       = (int*)alloc(N_NODES);
    float*    dinv       = (float*)alloc(N_NODES);
    unsigned* packed     = (unsigned*)alloc(N_NODES);
    float*    M          = (float*)alloc(VOCAB * H);
    int*      sorted_row = (int*)alloc(N_EDGES + 16);            // +16 zero pad
    float*    h          = (float*)alloc((size_t)N_NODES * H);
    unsigned short* qa   = (unsigned short*)alloc((size_t)N_NODES * H / 2);  // bf16
    unsigned short* qb   = (unsigned short*)alloc((size_t)N_NODES * H / 2);  // bf16

    // packed staging (int[N_EDGES] = 12.8 MB) aliases qa (dead until k_gather0 writes)
    int* staging = (int*)qa;

    const int B = 256;
    const int gT = (N_NODES + G0_TILE - 1) / G0_TILE;   // 1563
    const int gF = (N_NODES + FL_TILE - 1) / FL_TILE;   // 1563

    hipLaunchKernelGGL(k_init, dim3(1), dim3(1024), 0, stream, bcnt, sorted_row + N_EDGES);
    hipLaunchKernelGGL(k_bhist, dim3(PART_BLOCKS), dim3(256), 0, stream, col, bcnt, blkhist);
    hipLaunchKernelGGL(k_bscan, dim3(1), dim3(1024), 0, stream, bcnt, bbase, bcur);
    hipLaunchKernelGGL(k_binA, dim3(PART_BLOCKS), dim3(1024), 0, stream,
                       row, col, blkhist, bcur, staging);
    hipLaunchKernelGGL(k_binB, dim3(NBUCK), dim3(256), 0, stream, staging, bbase, x,
                       sorted_row, degi, row_start, dinv, packed);

    // layer 0: vocabulary-factored, S-bins + MFMA; also emits q = bf16(dinv*h)
    hipLaunchKernelGGL(k_premix, dim3(VOCAB), dim3(H), 0, stream, emb, conv_w, M);
    hipLaunchKernelGGL(k_gather0_mfma, dim3(gT), dim3(B), 0, stream,
                       sorted_row, row_start, degi, packed, M, dinv, conv_b, h, qa);

    // layers 1,2: fused gather + MFMA transform (h@W commutes with aggregation)
    hipLaunchKernelGGL(k_fused, dim3(gF), dim3(512), 0, stream,
                       sorted_row, row_start, degi, (const unsigned*)qa, dinv,
                       conv_w + (size_t)1 * H * H, conv_b + 1 * H, h, qb, 0);
    hipLaunchKernelGGL(k_fused, dim3(gF), dim3(512), 0, stream,
                       sorted_row, row_start, degi, (const unsigned*)qb, dinv,
                       conv_w + (size_t)2 * H * H, conv_b + 2 * H, h, qa, 1);

    hipLaunchKernelGGL(k_poolmlp, dim3(N_GRAPHS), dim3(64), 0, stream,
                       h, batch, w1, b1, w2, b2, w3, b3, out);

    (void)in_sizes; (void)n_in; (void)out_size; (void)ws_size;
}